// Round 9
// baseline (219.124 us; speedup 1.0000x reference)
//
#include <hip/hip_runtime.h>
#include <math.h>

typedef __attribute__((ext_vector_type(8))) short bf16x8;
typedef __attribute__((ext_vector_type(4))) float f32x4;
typedef __attribute__((ext_vector_type(4))) float vf4;
typedef __attribute__((ext_vector_type(4))) unsigned int u32x4;

__device__ __forceinline__ float wave_reduce(float v) {
#pragma unroll
    for (int off = 32; off > 0; off >>= 1) v += __shfl_down(v, off, 64);
    return v;
}

// truncation fp32->bf16 pack: two floats -> one dword (hi16(f1)<<16 | hi16(f0)).
__device__ __forceinline__ unsigned int pk_trunc(float f0, float f1) {
    unsigned u0 = __float_as_uint(f0), u1 = __float_as_uint(f1);
    return (u1 & 0xFFFF0000u) | (u0 >> 16);
}

// One angular K-step: 2x16B L2 loads per operand, norm FMAs, pack, MFMA.
__device__ __forceinline__ void ang_step(const vf4* __restrict__ aptr,
                                         const vf4* __restrict__ bptr, int st,
                                         bool va, bool vb,
                                         float& sa, float& sb, f32x4& acc) {
    vf4 a0 = {0.f, 0.f, 0.f, 0.f}, a1 = a0, b0 = a0, b1 = a0;
    if (va) { a0 = aptr[st * 8]; a1 = aptr[st * 8 + 1]; }
    if (vb) { b0 = bptr[st * 8]; b1 = bptr[st * 8 + 1]; }
    sa += a0.x * a0.x + a0.y * a0.y + a0.z * a0.z + a0.w * a0.w
        + a1.x * a1.x + a1.y * a1.y + a1.z * a1.z + a1.w * a1.w;
    sb += b0.x * b0.x + b0.y * b0.y + b0.z * b0.z + b0.w * b0.w
        + b1.x * b1.x + b1.y * b1.y + b1.z * b1.z + b1.w * b1.w;
    u32x4 ap, bp;
    ap.x = pk_trunc(a0.x, a0.y); ap.y = pk_trunc(a0.z, a0.w);
    ap.z = pk_trunc(a1.x, a1.y); ap.w = pk_trunc(a1.z, a1.w);
    bp.x = pk_trunc(b0.x, b0.y); bp.y = pk_trunc(b0.z, b0.w);
    bp.z = pk_trunc(b1.x, b1.y); bp.w = pk_trunc(b1.z, b1.w);
    bf16x8 af = __builtin_bit_cast(bf16x8, ap);
    bf16x8 bf = __builtin_bit_cast(bf16x8, bp);
    acc = __builtin_amdgcn_mfma_f32_16x16x32_bf16(af, bf, acc, 0, 0, 0);
}

// Fused angular+center. Center path is software-pipelined x4: per group, issue
// 4 independent y loads + 4 independent feat loads + 4 gathers, run 4 ang
// K-steps while they're in flight, then consume. Raises per-wave outstanding
// loads from ~1-2 to ~8-12 (R5 evidence: 980 GB/s at 12% peak = MLP-limited,
// not BW/VALU-limited). No launch_bounds min-occupancy pin: pipeline registers
// beat the last few waves of occupancy.
__global__ __launch_bounds__(256) void fused_kernel(const int* __restrict__ y,
                                                    const vf4* __restrict__ feat4,
                                                    const vf4* __restrict__ cent4,
                                                    float* __restrict__ partials,
                                                    int n4, int d4, float cen_scale,
                                                    int C, int ntile, int steps,
                                                    float ct, float ang_scale) {
    const int bid = blockIdx.x;
    const int lane = threadIdx.x & 63;
    const int wid = threadIdx.x >> 6;
    __shared__ float sm[4];

    // ---- angular setup (wave id == tile id) ----
    const int t = bid * 4 + wid;
    const int ntile2 = ntile * ntile;
    const bool hasTile = (t < ntile2);
    int ti = 0, tj = 0;
    const int n = lane & 15;
    const int quad = lane >> 4;
    const vf4* aptr = cent4;
    const vf4* bptr = cent4;
    bool va = false, vb = false;
    if (hasTile) {
        ti = t / ntile;
        tj = t - ti * ntile;
        const int ra = ti * 16 + n;
        const int rb = tj * 16 + n;
        va = ra < C;
        vb = rb < C;
        aptr = cent4 + (size_t)ra * d4 + quad * 2;
        bptr = cent4 + (size_t)rb * d4 + quad * 2;
    }
    f32x4 acc = {0.f, 0.f, 0.f, 0.f};
    float sa = 0.f, sb = 0.f;
    int st = 0;

    // ---- center path ----
    const int stride = gridDim.x * 256;
    const int i0 = bid * 256 + threadIdx.x;
    float cs = 0.f;

    const bool fast = ((n4 % stride) == 0) && ((stride % d4) == 0)
                      && (((n4 / stride) & 3) == 0);
    if (fast) {
        const int iters = n4 / stride;      // 16 at the expected shape
        const int rstep = stride / d4;
        int row = i0 / d4;
        const int col = i0 - row * d4;
        int i = i0;
        for (int g = 0; g < iters; g += 4) {
            // 4 independent y loads
            const int cls0 = y[row];
            const int cls1 = y[row + rstep];
            const int cls2 = y[row + 2 * rstep];
            const int cls3 = y[row + 3 * rstep];
            // 4 independent feat loads (read-once stream)
            vf4 f0 = __builtin_nontemporal_load(feat4 + i);
            vf4 f1 = __builtin_nontemporal_load(feat4 + i + stride);
            vf4 f2 = __builtin_nontemporal_load(feat4 + i + 2 * stride);
            vf4 f3 = __builtin_nontemporal_load(feat4 + i + 3 * stride);
            // 4 gathers (L2-resident centers; addresses ready from the y's)
            vf4 c0 = cent4[(size_t)cls0 * d4 + col];
            vf4 c1 = cent4[(size_t)cls1 * d4 + col];
            vf4 c2 = cent4[(size_t)cls2 * d4 + col];
            vf4 c3 = cent4[(size_t)cls3 * d4 + col];
            // 4 ang K-steps overlap the 12 in-flight loads
            if (hasTile && st < steps) {
                ang_step(aptr, bptr, st + 0, va, vb, sa, sb, acc);
                ang_step(aptr, bptr, st + 1, va, vb, sa, sb, acc);
                ang_step(aptr, bptr, st + 2, va, vb, sa, sb, acc);
                ang_step(aptr, bptr, st + 3, va, vb, sa, sb, acc);
                st += 4;
            }
            // consume
            float dx, dy, dz, dw;
            dx = f0.x - c0.x; dy = f0.y - c0.y; dz = f0.z - c0.z; dw = f0.w - c0.w;
            cs += dx * dx + dy * dy + dz * dz + dw * dw;
            dx = f1.x - c1.x; dy = f1.y - c1.y; dz = f1.z - c1.z; dw = f1.w - c1.w;
            cs += dx * dx + dy * dy + dz * dz + dw * dw;
            dx = f2.x - c2.x; dy = f2.y - c2.y; dz = f2.z - c2.z; dw = f2.w - c2.w;
            cs += dx * dx + dy * dy + dz * dz + dw * dw;
            dx = f3.x - c3.x; dy = f3.y - c3.y; dz = f3.z - c3.z; dw = f3.w - c3.w;
            cs += dx * dx + dy * dy + dz * dz + dw * dw;
            i += 4 * stride;
            row += 4 * rstep;
        }
    } else {
        // generic fallback
        for (int i = i0; i < n4; i += stride) {
            const int row = i / d4;
            const int col = i - row * d4;
            const int cls = y[row];
            vf4 f = __builtin_nontemporal_load(feat4 + i);
            vf4 c = cent4[(size_t)cls * d4 + col];
            float dx = f.x - c.x, dy = f.y - c.y, dz = f.z - c.z, dw = f.w - c.w;
            cs += dx * dx + dy * dy + dz * dz + dw * dw;
        }
    }

    // finish any remaining ang K-steps
    while (hasTile && st < steps) { ang_step(aptr, bptr, st, va, vb, sa, sb, acc); ++st; }

    float partial = cs * cen_scale;

    // ---- angular epilogue ----
    if (hasTile) {
        sa += __shfl_xor(sa, 16, 64); sa += __shfl_xor(sa, 32, 64);
        sb += __shfl_xor(sb, 16, 64); sb += __shfl_xor(sb, 32, 64);
        float di[4];
#pragma unroll
        for (int rr = 0; rr < 4; ++rr) di[rr] = __shfl(sa, quad * 4 + rr, 64);
        const int gj = tj * 16 + n;
        const float dj = sb;
        float local = 0.f;
#pragma unroll
        for (int rr = 0; rr < 4; ++rr) {
            const int gi = ti * 16 + quad * 4 + rr;
            if (gi < C && gj < C && gi != gj) {
                float sim = acc[rr] * rsqrtf(di[rr] * dj);
                float dlt = sim - ct;
                local += dlt * dlt;
            }
        }
        partial += local * ang_scale;
    }

    // block reduce -> plain store to partials[bid] (no atomics anywhere)
    float r = wave_reduce(partial);
    if (lane == 0) sm[wid] = r;
    __syncthreads();
    if (threadIdx.x == 0) {
        partials[bid] = sm[0] + sm[1] + sm[2] + sm[3];
    }
}

// Kernel 2: single block reduces nb partials -> out[0] (plain store).
__global__ __launch_bounds__(256) void reduce_kernel(const float* __restrict__ partials,
                                                     float* __restrict__ out, int nb) {
    __shared__ float sm[4];
    const int lane = threadIdx.x & 63;
    const int wid = threadIdx.x >> 6;
    float s = 0.f;
    for (int i = threadIdx.x; i < nb; i += 256) s += partials[i];
    s = wave_reduce(s);
    if (lane == 0) sm[wid] = s;
    __syncthreads();
    if (threadIdx.x == 0) out[0] = sm[0] + sm[1] + sm[2] + sm[3];
}

extern "C" void kernel_launch(void* const* d_in, const int* in_sizes, int n_in,
                              void* d_out, int out_size, void* d_ws, size_t ws_size,
                              hipStream_t stream) {
    const int* y = (const int*)d_in[0];
    const float* feat = (const float*)d_in[1];
    const float* centers = (const float*)d_in[2];

    const int B = in_sizes[0];
    const int D = in_sizes[1] / B;
    const int C = in_sizes[2] / D;
    const int d4 = D / 4;
    const int ntile = (C + 15) / 16;

    // ct = costheta(C): static recurrence in double, matches Python reference.
    const int nd = C - 1;
    double r = 0.0;
    if (nd >= 2) {
        r = 0.5;
        for (int i = 3; i <= nd; ++i) r = 0.5 / sqrt(1.0 - r * r);
    }
    const float ct = (float)(2.0 * r * r - 1.0);

    const float cen_scale = (float)(0.5 / (double)B);
    const float ang_scale = (float)(1.0 / (0.5 * (double)C * (double)(C - 1)));

    float* partials = (float*)d_ws;
    const int nb = 2048;   // 8192 waves cover 3969 ang tiles; 16 center iters/thread

    fused_kernel<<<nb, 256, 0, stream>>>(
        y, (const vf4*)feat, (const vf4*)centers, partials,
        B * d4, d4, cen_scale, C, ntile, D / 32, ct, ang_scale);

    reduce_kernel<<<1, 256, 0, stream>>>(partials, (float*)d_out, nb);
}

// Round 10
// 208.783 us; speedup vs baseline: 1.0495x; 1.0495x over previous
//
#include <hip/hip_runtime.h>
#include <math.h>

typedef __attribute__((ext_vector_type(8))) short bf16x8;
typedef __attribute__((ext_vector_type(16))) float f32x16;
typedef __attribute__((ext_vector_type(4))) float vf4;
typedef __attribute__((ext_vector_type(4))) unsigned int u32x4;

__device__ __forceinline__ float wave_reduce(float v) {
#pragma unroll
    for (int off = 32; off > 0; off >>= 1) v += __shfl_down(v, off, 64);
    return v;
}

// truncation fp32->bf16 pack: two floats -> one dword (hi16(f1)<<16 | hi16(f0)).
__device__ __forceinline__ unsigned int pk_trunc(float f0, float f1) {
    unsigned u0 = __float_as_uint(f0), u1 = __float_as_uint(f1);
    return (u1 & 0xFFFF0000u) | (u0 >> 16);
}

// Fused angular+center.
// Ang: one 32x32 gram tile per wave via v_mfma_f32_32x32x16_bf16 (1024 tiles,
// 12.5% of the 8192 waves). Halves ang L2 traffic (254->128 MB) and ang
// VMEM/VALU vs the 16x16 version, same MFMA cycles. fp32 centers converted
// in-flight (truncation); row norms in-register.
// Center: simple grid-stride feat stream (R8 loop; R9's deep pipeline
// regressed -> reverted).
__global__ __launch_bounds__(256) void fused_kernel(const int* __restrict__ y,
                                                    const vf4* __restrict__ feat4,
                                                    const vf4* __restrict__ cent4,
                                                    float* __restrict__ partials,
                                                    int n4, int d4, float cen_scale,
                                                    int C, int ntile32, int steps16,
                                                    float ct, float ang_scale) {
    const int bid = blockIdx.x;
    const int lane = threadIdx.x & 63;
    const int wid = threadIdx.x >> 6;
    __shared__ float sm[4];

    float partial = 0.f;

    // ---------------- angular: one 32x32 tile per wave ----------------
    const int t = bid * 4 + wid;            // global wave id == tile id
    const int ntile2 = ntile32 * ntile32;
    if (t < ntile2) {
        const int ti = t / ntile32;
        const int tj = t - ti * ntile32;
        const int m = lane & 31;            // A/B row within panel
        const int half = lane >> 5;         // k-half selector
        const int ra = ti * 32 + m;
        const int rb = tj * 32 + m;
        const bool va = ra < C;
        const bool vb = rb < C;
        const vf4* aptr = cent4 + (size_t)ra * d4 + half * 2;
        const vf4* bptr = cent4 + (size_t)rb * d4 + half * 2;
        f32x16 acc;
#pragma unroll
        for (int k = 0; k < 16; ++k) acc[k] = 0.f;
        float sa = 0.f, sb = 0.f;
#pragma unroll 4
        for (int st = 0; st < steps16; ++st) {
            vf4 a0 = {0.f, 0.f, 0.f, 0.f}, a1 = a0, b0 = a0, b1 = a0;
            if (va) { a0 = aptr[st * 4]; a1 = aptr[st * 4 + 1]; }
            if (vb) { b0 = bptr[st * 4]; b1 = bptr[st * 4 + 1]; }
            sa += a0.x * a0.x + a0.y * a0.y + a0.z * a0.z + a0.w * a0.w
                + a1.x * a1.x + a1.y * a1.y + a1.z * a1.z + a1.w * a1.w;
            sb += b0.x * b0.x + b0.y * b0.y + b0.z * b0.z + b0.w * b0.w
                + b1.x * b1.x + b1.y * b1.y + b1.z * b1.z + b1.w * b1.w;
            u32x4 ap, bp;
            ap.x = pk_trunc(a0.x, a0.y); ap.y = pk_trunc(a0.z, a0.w);
            ap.z = pk_trunc(a1.x, a1.y); ap.w = pk_trunc(a1.z, a1.w);
            bp.x = pk_trunc(b0.x, b0.y); bp.y = pk_trunc(b0.z, b0.w);
            bp.z = pk_trunc(b1.x, b1.y); bp.w = pk_trunc(b1.z, b1.w);
            bf16x8 af = __builtin_bit_cast(bf16x8, ap);
            bf16x8 bf = __builtin_bit_cast(bf16x8, bp);
            acc = __builtin_amdgcn_mfma_f32_32x32x16_bf16(af, bf, acc, 0, 0, 0);
        }
        // combine the two k-halves of each row norm: lanes l and l^32 share row l&31
        sa += __shfl_xor(sa, 32, 64);
        sb += __shfl_xor(sb, 32, 64);
        // C/D layout (measured m74/m101): col = lane&31, row = (reg&3)+8*(reg>>2)+4*half
        const int gj = tj * 32 + m;
        const float dj = sb;                // norm of B row gj (col of this lane)
        float local = 0.f;
#pragma unroll
        for (int reg = 0; reg < 16; ++reg) {
            const int r = (reg & 3) + 8 * (reg >> 2) + 4 * half;
            const int gi = ti * 32 + r;
            const float di = __shfl(sa, r, 64);   // lane r holds norm of A row r
            if (gi < C && gj < C && gi != gj) {
                float sim = acc[reg] * rsqrtf(di * dj);
                float dlt = sim - ct;
                local += dlt * dlt;
            }
        }
        partial = local * ang_scale;
    }

    // ---------------- center: grid-stride over float4 elements of feat ----------------
    {
        const int stride = gridDim.x * 256;
        float cs = 0.f;
        int i = bid * 256 + threadIdx.x;
        if ((stride % d4) == 0) {
            if (i < n4) {
                int row = i / d4;
                const int col = i - row * d4;
                const int rstep = stride / d4;
                for (; i < n4; i += stride, row += rstep) {
                    const int cls = y[row];
                    vf4 f = __builtin_nontemporal_load(feat4 + i);
                    vf4 c = cent4[(size_t)cls * d4 + col];
                    float dx = f.x - c.x, dy = f.y - c.y, dz = f.z - c.z, dw = f.w - c.w;
                    cs += dx * dx + dy * dy + dz * dz + dw * dw;
                }
            }
        } else {
            for (; i < n4; i += stride) {
                int row = i / d4;
                int col = i - row * d4;
                const int cls = y[row];
                vf4 f = __builtin_nontemporal_load(feat4 + i);
                vf4 c = cent4[(size_t)cls * d4 + col];
                float dx = f.x - c.x, dy = f.y - c.y, dz = f.z - c.z, dw = f.w - c.w;
                cs += dx * dx + dy * dy + dz * dz + dw * dw;
            }
        }
        partial += cs * cen_scale;
    }

    // block reduce -> plain store to partials[bid] (no atomics anywhere)
    float r = wave_reduce(partial);
    if (lane == 0) sm[wid] = r;
    __syncthreads();
    if (threadIdx.x == 0) {
        partials[bid] = sm[0] + sm[1] + sm[2] + sm[3];
    }
}

// Kernel 2: single block reduces nb partials -> out[0] (plain store).
__global__ __launch_bounds__(256) void reduce_kernel(const float* __restrict__ partials,
                                                     float* __restrict__ out, int nb) {
    __shared__ float sm[4];
    const int lane = threadIdx.x & 63;
    const int wid = threadIdx.x >> 6;
    float s = 0.f;
    for (int i = threadIdx.x; i < nb; i += 256) s += partials[i];
    s = wave_reduce(s);
    if (lane == 0) sm[wid] = s;
    __syncthreads();
    if (threadIdx.x == 0) out[0] = sm[0] + sm[1] + sm[2] + sm[3];
}

extern "C" void kernel_launch(void* const* d_in, const int* in_sizes, int n_in,
                              void* d_out, int out_size, void* d_ws, size_t ws_size,
                              hipStream_t stream) {
    const int* y = (const int*)d_in[0];
    const float* feat = (const float*)d_in[1];
    const float* centers = (const float*)d_in[2];

    const int B = in_sizes[0];
    const int D = in_sizes[1] / B;
    const int C = in_sizes[2] / D;
    const int d4 = D / 4;
    const int ntile32 = (C + 31) / 32;

    // ct = costheta(C): static recurrence in double, matches Python reference.
    const int nd = C - 1;
    double r = 0.0;
    if (nd >= 2) {
        r = 0.5;
        for (int i = 3; i <= nd; ++i) r = 0.5 / sqrt(1.0 - r * r);
    }
    const float ct = (float)(2.0 * r * r - 1.0);

    const float cen_scale = (float)(0.5 / (double)B);
    const float ang_scale = (float)(1.0 / (0.5 * (double)C * (double)(C - 1)));

    float* partials = (float*)d_ws;
    const int nb = 2048;   // 8192 waves; 1024 ang tiles (12.5% of waves); 16 center iters/thread

    fused_kernel<<<nb, 256, 0, stream>>>(
        y, (const vf4*)feat, (const vf4*)centers, partials,
        B * d4, d4, cen_scale, C, ntile32, D / 16, ct, ang_scale);

    reduce_kernel<<<1, 256, 0, stream>>>(partials, (float*)d_out, nb);
}